// Round 7
// baseline (6430.962 us; speedup 1.0000x reference)
//
#include <hip/hip_runtime.h>
#include <hip/hip_fp16.h>
#include <cstdint>
#include <cstddef>

// ---------------------------------------------------------------------------
// Tacotron2-style decoder, persistent kernel. 256 blocks x 512 threads,
// 1 block/CU (~157KB LDS). TWO phases per step (303 grid barriers vs 452):
//   A(t): LSTM0(t)  [blk 0-127; X=[attc/S|prenet|h0(t-1)] K=1792 fused
//                    Wi0|Wh0 fp16 in LDS; epilogue writes h0(t) + rank-8
//                    q-partials qp from a 4KB LDS Wq slice -- NO atomics,
//                    NO per-block 256KB Wq reads (r2/r3 lessons)]
//       | LSTM1(t-1)[blk 128-255; X=[h0(t-1)|h1(t-2)] K=2048 fused Wi1|Wh1]
//   B(t): attn(t+1) [blk 0-63; q = contiguous qp reduce; r1 attention body;
//                    window = cumg(t-1) + attw(t) computed locally]
//       | cum/attw(t) [64-71] | outstop(t-1) [72-152] | zero attc [153-160]
// State parity-buffered (h0,h1,attc,attcn,uw,cumg,Sw). Barrier: r5 all-scan.
// (Resubmission of r6 -- container acquisition failed; kernel unchanged.)
// ---------------------------------------------------------------------------

#define NB 256
#define NT 512

#define TE   512
#define DINz 512
#define TDz  150
#define ODz  80
#define PREz 256
#define ATz  128
#define LOCz 32
#define KFz  31

// workspace offsets (floats)
#define OF_P     0         // prenet [1200][256]
#define OF_PM    307200    // pmT [64 blk][128 a][64 il]
#define OF_QP    831488    // qp [128 a][8 b][128 ublk]
#define OF_U     962560    // uw [2][8][512]
#define OF_CUM   970752    // cumg [2][8][512]
#define OF_ATTC  978944    // attc [2][8][512] (atomic accum)
#define OF_ATTCN 987136    // attcn [2][8][512] (normalized, for outstop)
#define OF_S     995328    // Sw [2][8]
#define OF_H0    995344    // h0 [2][8][1024]
#define OF_C0    1011728   // c0 [8][1024]
#define OF_H1    1019920   // h1 [2][8][1024]
#define OF_C1    1036304   // c1 [8][1024]
#define OF_BAR   1044496   // 4608 ints: slots[256*16]

// LDS offsets (floats)
#define OFF_X0   0         // X chunk buf A [8][256]
#define OFF_X1   2048      // X chunk buf B
#define OFF_EX   4096      // reduce exchange [256]
#define OFF_EXG  4352      // gate exchange [256]
#define OFF_HN   4608      // h0-new stage [8 b][8 ul]
#define OFF_WQS  4672      // Wq slice [128 a][8 ul] fp32 (blk<128)
#define OFF_W    5696      // fused W fp16: blk<128 32x1792 (28672f);
                           //               blk>=128 32x2048 (32768f)
#define OFF_F    34368     // attn F = W_loc@filters (3968)  (blk<64)
#define OFF_V    38336     // attn v (128)
#define OFF_CW   38464     // cum window (96)
#define OFF_QS   38560     // q slab (128)
#define OFF_PART 38688     // partials [64 il][8 ag] (512)
#define OFF_UU   39200     // u stage (64)
#define SM_TOTF  39264     // 157056 B

#define AG __HIP_MEMORY_SCOPE_AGENT

__device__ __forceinline__ float ldg_sc1(const float* p){
  return __hip_atomic_load(p, __ATOMIC_RELAXED, AG);
}
__device__ __forceinline__ void stg_sc1(float* p, float v){
  __hip_atomic_store(p, v, __ATOMIC_RELAXED, AG);
}
__device__ __forceinline__ float4 ldg4_sc1(const float* p){
  float4 r; r.x=ldg_sc1(p); r.y=ldg_sc1(p+1); r.z=ldg_sc1(p+2); r.w=ldg_sc1(p+3);
  return r;
}
__device__ __forceinline__ void stg4_sc1(float* p, float4 v){
  stg_sc1(p, v.x); stg_sc1(p+1, v.y); stg_sc1(p+2, v.z); stg_sc1(p+3, v.w);
}
__device__ __forceinline__ float fsig_(float x){ return 1.f/(1.f + __expf(-x)); }
__device__ __forceinline__ float ftanh_(float x){
  x = fminf(10.f, fmaxf(-10.f, x));
  float e = __expf(2.f*x);
  return (e - 1.f) / (e + 1.f);
}

// -------- all-blocks-scan grid barrier (r5, validated) ---------------------
__device__ __forceinline__ void grid_barrier(int* bar, int target){
  asm volatile("s_waitcnt vmcnt(0) lgkmcnt(0)" ::: "memory");
  __syncthreads();
  if (threadIdx.x == 0)
    __hip_atomic_store(bar + (blockIdx.x << 4), target, __ATOMIC_RELAXED, AG);
  for (;;){
    int ok = 1;
    if (threadIdx.x < 256)
      ok = (__hip_atomic_load(bar + (threadIdx.x << 4), __ATOMIC_RELAXED, AG) >= target);
    if (__syncthreads_and(ok)) break;
    __builtin_amdgcn_s_sleep(1);
  }
}
__device__ __forceinline__ void grid_barrier_heavy(int* bar, int target){
  asm volatile("s_waitcnt vmcnt(0) lgkmcnt(0)" ::: "memory");
  __syncthreads();
  if (threadIdx.x == 0){
    __builtin_amdgcn_fence(__ATOMIC_RELEASE, "agent");
    __hip_atomic_store(bar + (blockIdx.x << 4), target, __ATOMIC_RELAXED, AG);
  }
  for (;;){
    int ok = 1;
    if (threadIdx.x < 256)
      ok = (__hip_atomic_load(bar + (threadIdx.x << 4), __ATOMIC_RELAXED, AG) >= target);
    if (__syncthreads_and(ok)) break;
    __builtin_amdgcn_s_sleep(1);
  }
  if (threadIdx.x == 0)
    __builtin_amdgcn_fence(__ATOMIC_ACQUIRE, "agent");
  __syncthreads();
}

// init loaders: fused fp16 weight tiles (gate-mapped rows), from r2 (validated)
__device__ void load_wc0(float* smW, const float* __restrict__ Wi0,
                         const float* __restrict__ Wh0, int u0){
  __half* dst = (__half*)smW;
  for (int idx = threadIdx.x; idx < 32*448; idx += NT){
    int r = idx / 448, c4 = (idx - r*448) << 2;
    int grow = ((r>>3)<<10) + u0 + (r&7);
    const float* src = (c4 < 768) ? (Wi0 + (size_t)grow*768 + c4)
                                  : (Wh0 + (size_t)grow*1024 + (c4-768));
    float4 w = *(const float4*)src;
    __half* d = dst + (size_t)r*1792 + c4;
    d[0]=__float2half_rn(w.x); d[1]=__float2half_rn(w.y);
    d[2]=__float2half_rn(w.z); d[3]=__float2half_rn(w.w);
  }
}
__device__ void load_wc1(float* smW, const float* __restrict__ Wi1,
                         const float* __restrict__ Wh1, int u0){
  __half* dst = (__half*)smW;
  for (int idx = threadIdx.x; idx < 32*512; idx += NT){
    int r = idx >> 9, c4 = (idx & 511) << 2;
    int grow = ((r>>3)<<10) + u0 + (r&7);
    const float* src = (c4 < 1024) ? (Wi1 + (size_t)grow*1024 + c4)
                                   : (Wh1 + (size_t)grow*1024 + (c4-1024));
    float4 w = *(const float4*)src;
    __half* d = dst + (size_t)r*2048 + c4;
    d[0]=__float2half_rn(w.x); d[1]=__float2half_rn(w.y);
    d[2]=__float2half_rn(w.z); d[3]=__float2half_rn(w.w);
  }
}

// shuffle-reduce 32 k-slice partials -> dot for tid<256 (row=tid>>3, b=tid&7)
__device__ __forceinline__ float reduce_dot(float* sm, float (&acc)[2][8]){
  const int tid = threadIdx.x;
  const int s = tid & 31, pos = tid >> 5;
  #pragma unroll
  for (int i=0;i<2;++i){
    #pragma unroll
    for (int b=0;b<8;++b){
      float v = acc[i][b];
      v += __shfl_xor(v, 16, 64);
      v += __shfl_xor(v,  8, 64);
      v += __shfl_xor(v,  4, 64);
      v += __shfl_xor(v,  2, 64);
      v += __shfl_xor(v,  1, 64);
      acc[i][b] = v;
    }
  }
  if (s == 0){
    #pragma unroll
    for (int i=0;i<2;++i)
      #pragma unroll
      for (int b=0;b<8;++b)
        sm[OFF_EX + ((((pos<<1)+i)<<3) | b)] = acc[i][b];
  }
  __syncthreads();
  return (tid < 256) ? sm[OFF_EX + tid] : 0.f;
}

// GEMM: out[row 0..31][b 0..7] = sum_k Wlds[row][k] * X[b][k]. (r2, validated)
template<int NCH>
__device__ float gemm_core(float* sm, const __half* __restrict__ wlds,
                           float4 (&xreg)[NCH]){
  const int tid = threadIdx.x;
  const int s = tid & 31, pos = tid >> 5;
  const int xb = tid >> 6, xcol = (tid & 63) << 2;
  constexpr int K = NCH << 8;
  float acc[2][8];
  #pragma unroll
  for (int i=0;i<2;++i)
    #pragma unroll
    for (int b=0;b<8;++b) acc[i][b] = 0.f;
  *(float4*)&sm[OFF_X0 + (xb<<8) + xcol] = xreg[0];
  __syncthreads();
  #pragma unroll
  for (int ch=0; ch<NCH; ++ch){
    if (ch+1 < NCH)
      *(float4*)&sm[(((ch+1)&1) ? OFF_X1 : OFF_X0) + (xb<<8) + xcol] =
          xreg[(ch+1 < NCH) ? ch+1 : 0];
    const float* xbase = &sm[((ch&1) ? OFF_X1 : OFF_X0)];
    const __half* wch = wlds + (ch<<8);
    #pragma unroll
    for (int j=0;j<2;++j){
      const int k = (j<<7) + (s<<2);
      float4 xv[8];
      #pragma unroll
      for (int b=0;b<8;++b) xv[b] = *(const float4*)&xbase[(b<<8) + k];
      #pragma unroll
      for (int i=0;i<2;++i){
        const int row = (pos<<1) + i;
        uint2 w2 = *(const uint2*)&wch[(size_t)row*K + k];
        __half2 ha = *reinterpret_cast<const __half2*>(&w2.x);
        __half2 hb = *reinterpret_cast<const __half2*>(&w2.y);
        float2 fa = __half22float2(ha);
        float2 fb = __half22float2(hb);
        #pragma unroll
        for (int b=0;b<8;++b){
          acc[i][b] = fmaf(fa.x, xv[b].x, acc[i][b]);
          acc[i][b] = fmaf(fa.y, xv[b].y, acc[i][b]);
          acc[i][b] = fmaf(fb.x, xv[b].z, acc[i][b]);
          acc[i][b] = fmaf(fb.y, xv[b].w, acc[i][b]);
        }
      }
    }
    __syncthreads();
  }
  return reduce_dot(sm, acc);
}

__device__ __forceinline__ float prefetch_h(const float* h, int u0){
  const int tid = threadIdx.x;
  if (tid >= 64) return 0.f;
  return ldg_sc1(&h[((tid&7)<<10) + u0 + (tid>>3)]);
}

// one output row per wave: rr = b*81 + r (r==80 -> stop). attcn pre-normalized.
__device__ void outstop_wave(int rr, int tp,
    const float* __restrict__ feat_W, const float* __restrict__ stop_W,
    const float* __restrict__ stop_b, const float* __restrict__ h1b,
    const float* __restrict__ attcn, float* __restrict__ d_out)
{
  if (rr >= 648) return;
  int b = rr / 81, r = rr - 81*b;
  int lane = threadIdx.x & 63;
  const float4* Wr = (const float4*)((r < 80) ? (feat_W + (size_t)r*1536) : stop_W);
  float acc = 0.f;
  #pragma unroll
  for (int j=0;j<4;++j){
    int p = lane + (j<<6);
    float4 w = Wr[p], x = ldg4_sc1(h1b + (b<<10) + (p<<2));
    acc = fmaf(w.x,x.x, fmaf(w.y,x.y, fmaf(w.z,x.z, fmaf(w.w,x.w, acc))));
  }
  #pragma unroll
  for (int j=4;j<6;++j){
    int p = lane + (j<<6);
    float4 w = Wr[p], x = ldg4_sc1(attcn + (b<<9) + ((p-256)<<2));
    acc = fmaf(w.x,x.x, fmaf(w.y,x.y, fmaf(w.z,x.z, fmaf(w.w,x.w, acc))));
  }
  acc += __shfl_down(acc, 32, 64);
  acc += __shfl_down(acc, 16, 64);
  acc += __shfl_down(acc,  8, 64);
  acc += __shfl_down(acc,  4, 64);
  acc += __shfl_down(acc,  2, 64);
  acc += __shfl_down(acc,  1, 64);
  if (lane == 0){
    if (r < 80) d_out[((size_t)b*TDz + tp)*ODz + r] = acc;
    else        d_out[96000 + (size_t)b*TDz + tp] = acc + stop_b[0];
  }
}

// attention for step tau = t+1 (t = -1 is the prologue: zero window, q from
// zeroed qp). r1 body + parity indices + contiguous qp reduce.
__device__ void attn_phase(float* sm, const float* __restrict__ memory,
                           const int* __restrict__ mlen,
                           const float* __restrict__ pmT, const float* __restrict__ qp,
                           float* __restrict__ uw, const float* __restrict__ cumg,
                           float* __restrict__ attc, float* __restrict__ Sw,
                           int blk, int t)
{
  const int tid = threadIdx.x;
  const int ab = blk >> 3, ai0 = (blk & 7) << 6;
  const int il = tid & 63, ag = tid >> 6;
  const int tp = (t + 1) & 1;
  // q[a] = sum_u qp[a][ab][u]  (contiguous 128-float rows)
  {
    int a = tid >> 2, qt = tid & 3;
    const float* qrow = qp + (((size_t)((a<<3) + ab)) << 7) + (qt<<5);
    float s = 0.f;
    #pragma unroll
    for (int i=0;i<8;++i){
      float4 v = ldg4_sc1(qrow + (i<<2));
      s += v.x + v.y + v.z + v.w;
    }
    s += __shfl_xor(s, 1, 64);
    s += __shfl_xor(s, 2, 64);
    if (qt == 0) sm[OFF_QS + a] = s;
  }
  // cum window through step t: cumg(t-1) + attw(t) computed locally
  if (tid < 94){
    float v = 0.f;
    int gi = ai0 - 15 + tid;
    if (t >= 0 && gi >= 0 && gi < TE){
      float inv = 1.f / ldg_sc1(&Sw[((t&1)<<3) + ab]);
      v = ldg_sc1(&cumg[(((t&1)^1)<<12) + (ab<<9) + gi])
        + ldg_sc1(&uw[((t&1)<<12) + (ab<<9) + gi]) * inv;
    }
    sm[OFF_CW + tid] = v;
  }
  __syncthreads();
  float part = 0.f;
  #pragma unroll
  for (int j=0;j<16;++j){
    int a = (ag<<4) + j;
    const float* fb = &sm[OFF_F + a*KFz];
    float conv = 0.f;
    #pragma unroll
    for (int k=0;k<KFz;++k) conv = fmaf(fb[k], sm[OFF_CW + il + k], conv);
    float pv = pmT[((size_t)blk<<13) + (a<<6) + il];
    part = fmaf(sm[OFF_V + a], ftanh_(pv + sm[OFF_QS + a] + conv), part);
  }
  sm[OFF_PART + (il<<3) + ag] = part;
  __syncthreads();
  if (tid < 64){
    float e = 0.f;
    #pragma unroll
    for (int k=0;k<8;++k) e += sm[OFF_PART + (tid<<3) + k];
    int gi = ai0 + tid;
    float uu = (gi < mlen[ab]) ? __expf(e) : 0.f;
    stg_sc1(&uw[(tp<<12) + (ab<<9) + gi], uu);
    sm[OFF_UU + tid] = uu;
  }
  __syncthreads();
  if (tid == 0){
    float ssum = 0.f;
    #pragma unroll
    for (int k=0;k<64;++k) ssum += sm[OFF_UU + k];
    atomicAdd(&Sw[(tp<<3) + ab], ssum);
  }
  {
    float acc = 0.f;
    const float* mrow = memory + (size_t)((ab<<9)+ai0)*DINz + tid;
    #pragma unroll 4
    for (int i=0;i<64;++i)
      acc = fmaf(sm[OFF_UU + i], mrow[(size_t)i*DINz], acc);
    atomicAdd(&attc[(tp<<12) + (ab<<9) + tid], acc);
  }
}

extern "C" __global__ void __launch_bounds__(NT, 1) dec_kernel(
  const float* __restrict__ memory, const int* __restrict__ mlen, const float* __restrict__ targets,
  const float* __restrict__ W_mem, const float* __restrict__ W_q, const float* __restrict__ W_loc,
  const float* __restrict__ loc_f, const float* __restrict__ attn_v, const float* __restrict__ attn_b,
  const float* __restrict__ pre_W1, const float* __restrict__ pre_b1,
  const float* __restrict__ pre_W2, const float* __restrict__ pre_b2,
  const float* __restrict__ Wi0, const float* __restrict__ Wh0, const float* __restrict__ bl0,
  const float* __restrict__ Wi1, const float* __restrict__ Wh1, const float* __restrict__ bl1,
  const float* __restrict__ feat_W, const float* __restrict__ stop_W, const float* __restrict__ stop_b,
  float* __restrict__ d_out, float* __restrict__ ws)
{
  __shared__ float sm[SM_TOTF];
  const int blk = blockIdx.x, tid = threadIdx.x;

  float* Pw    = ws + OF_P;
  float* pmT   = ws + OF_PM;
  float* qp    = ws + OF_QP;
  float* uw    = ws + OF_U;
  float* cumg  = ws + OF_CUM;
  float* attc  = ws + OF_ATTC;
  float* attcn = ws + OF_ATTCN;
  float* Sw    = ws + OF_S;
  float* h0 = ws + OF_H0; float* c0 = ws + OF_C0;
  float* h1 = ws + OF_H1; float* c1 = ws + OF_C1;
  int* bar = (int*)(ws + OF_BAR);
  int bt = 0;

  const bool is_l = (blk < 128);
  const bool is_attn = (blk < 64);

  // ------------------------- INIT (every launch) ---------------------------
  {
    const int gs = NB*NT;
    const int gid = blk*NT + tid;
    // zero all dynamic state: qp..c1 contiguous
    for (int i = gid; i < (OF_BAR - OF_QP); i += gs) ws[OF_QP + i] = 0.f;

    if (is_attn){
      // pmT FIRST (scratch sm[0..8255] overlaps W region)
      const int ab  = blk >> 3;
      const int ai0 = (blk & 7) << 6;
      const int il  = tid & 63;
      const int ag  = tid >> 6;
      float pacc[16];
      #pragma unroll
      for (int j=0;j<16;++j) pacc[j] = 0.f;
      for (int dc=0; dc<4; ++dc){
        for (int idx = tid; idx < 8192; idx += NT){
          int r = idx >> 7, d = idx & 127;
          sm[r*129 + d] = memory[(size_t)((ab<<9)+ai0+r)*DINz + (dc<<7) + d];
        }
        __syncthreads();
        #pragma unroll
        for (int j=0;j<16;++j){
          int a = (ag<<4) + j;
          const float* wr = W_mem + (size_t)a*DINz + (dc<<7);
          const float* mr = &sm[il*129];
          float acc = 0.f;
          for (int d=0; d<128; d+=4){
            acc = fmaf(mr[d  ], wr[d  ], acc);
            acc = fmaf(mr[d+1], wr[d+1], acc);
            acc = fmaf(mr[d+2], wr[d+2], acc);
            acc = fmaf(mr[d+3], wr[d+3], acc);
          }
          pacc[j] += acc;
        }
        __syncthreads();
      }
      #pragma unroll
      for (int j=0;j<16;++j){
        int a = (ag<<4) + j;
        pmT[((size_t)blk<<13) + (a<<6) + il] = pacc[j] + attn_b[a];
      }
      __syncthreads();
    }

    // persistent fp16 weight tiles (+ Wq slice for L blocks)
    if (is_l){
      load_wc0(&sm[OFF_W], Wi0, Wh0, blk<<3);
      for (int i = tid; i < 1024; i += NT)
        sm[OFF_WQS + i] = W_q[((size_t)(i>>3)<<10) + (blk<<3) + (i&7)];
    } else {
      load_wc1(&sm[OFF_W], Wi1, Wh1, (blk-128)<<3);
    }

    if (is_attn){
      for (int idx = tid; idx < ATz*KFz; idx += NT){
        int a = idx / KFz, k = idx - a*KFz;
        float s2 = 0.f;
        #pragma unroll
        for (int c2=0;c2<LOCz;++c2) s2 = fmaf(W_loc[(a<<5)+c2], loc_f[c2*KFz+k], s2);
        sm[OFF_F + idx] = s2;
      }
      if (tid < 128) sm[OFF_V + tid] = attn_v[tid];
      __syncthreads();
    }

    // prenet for all (t,b) pairs; scratch sm[0..1023]
    const int th = tid >> 8, t2 = tid & 255, base = th << 9;
    for (int it=0; it<3; ++it){
      int pp2 = (blk<<1) + th + (it<<9);
      bool act = pp2 < 1200;
      if (act && t2 < ODz){
        int tt = pp2 >> 3, bb = pp2 & 7;
        sm[base + t2] = (tt==0) ? 0.f : targets[((size_t)bb*TDz + (tt-1))*ODz + t2];
      }
      __syncthreads();
      if (act){
        float a1 = pre_b1[t2];
        for (int k=0;k<ODz;++k) a1 = fmaf(pre_W1[t2*ODz+k], sm[base+k], a1);
        sm[base + 128 + t2] = fmaxf(a1, 0.f);
      }
      __syncthreads();
      if (act){
        float a2 = pre_b2[t2];
        for (int k=0;k<PREz;++k) a2 = fmaf(pre_W2[(t2<<8)+k], sm[base+128+k], a2);
        Pw[((size_t)pp2<<8) + t2] = fmaxf(a2, 0.f);
      }
      __syncthreads();
    }
  }
  grid_barrier_heavy(bar, ++bt);

  // ---- prologue B(-1): attn(0) (q=0 from zeroed qp, window=0) -------------
  if (is_attn)
    attn_phase(sm, memory, mlen, pmT, qp, uw, cumg, attc, Sw, blk, -1);
  grid_barrier(bar, ++bt);

  // ------------------------------ MAIN LOOP (2 phases) ---------------------
  for (int t = 0; t < TDz; ++t){
    const int p = t & 1, pm = p ^ 1;

    // ---- Phase A(t): LSTM0(t) [0-127] | LSTM1(t-1) [128-255] --------------
    if (is_l){
      const int u0 = blk << 3;
      const int xb = tid >> 6, xcol = (tid & 63) << 2;
      float sv = ldg_sc1(Sw + (p<<3) + xb);
      float hold = prefetch_h(h0 + (pm<<13), u0);
      float4 xr[7];
      xr[0] = ldg4_sc1(attc + (p<<12) + (xb<<9) + xcol);
      xr[1] = ldg4_sc1(attc + (p<<12) + (xb<<9) + 256 + xcol);
      xr[2] = *(const float4*)(Pw + ((size_t)t<<11) + (xb<<8) + xcol);
      #pragma unroll
      for (int c=0;c<4;++c) xr[3+c] = ldg4_sc1(h0 + (pm<<13) + (xb<<10) + (c<<8) + xcol);
      float inv = 1.f / sv;
      xr[0].x*=inv; xr[0].y*=inv; xr[0].z*=inv; xr[0].w*=inv;
      xr[1].x*=inv; xr[1].y*=inv; xr[1].z*=inv; xr[1].w*=inv;
      if (blk == 0){  // publish normalized att_c(t) for outstop(t) in B(t+1)
        float* an = attcn + (p<<12) + (xb<<9) + xcol;
        stg4_sc1(an, xr[0]);
        stg4_sc1(an + 256, xr[1]);
      }
      if (blk == 1 && tid < 8) stg_sc1(&Sw[(pm<<3)+tid], 0.f);  // for attn(t+1)
      float dot = gemm_core<7>(sm, (const __half*)&sm[OFF_W], xr);
      if (tid < 256){
        int row32 = tid >> 3, gate = row32 >> 3, ul = row32 & 7;
        sm[OFF_EXG + tid] = dot + bl0[(gate<<10) + u0 + ul];
      }
      __syncthreads();
      if (tid < 64){
        float gi = sm[OFF_EXG + tid];
        float gf = sm[OFF_EXG + 64 + tid];
        float gg = sm[OFF_EXG + 128 + tid];
        float go = sm[OFF_EXG + 192 + tid];
        int ul2 = tid >> 3, b2 = tid & 7;
        int hi = (b2<<10) + u0 + ul2;
        float co = c0[hi];
        float cn = fsig_(gf)*co + fsig_(gi)*ftanh_(gg);
        float hn = fsig_(go)*ftanh_(cn);
        c0[hi] = 0.9f*cn + 0.1f*co;
        float hz = 0.9f*hn + 0.1f*hold;
        stg_sc1(h0 + (p<<13) + hi, hz);
        sm[OFF_HN + (b2<<3) + ul2] = hz;
      }
      __syncthreads();
      {  // qp[a][b][blk] = sum_ul Wq[a][u0+ul] * h0new[ul][b]
        int pr = tid << 1;
        #pragma unroll
        for (int e=0;e<2;++e){
          int idx = pr + e;
          int a = idx >> 3, b = idx & 7;
          float qv = 0.f;
          #pragma unroll
          for (int ul=0; ul<8; ++ul)
            qv = fmaf(sm[OFF_WQS + (a<<3) + ul], sm[OFF_HN + (b<<3) + ul], qv);
          stg_sc1(&qp[((size_t)idx<<7) + blk], qv);
        }
      }
    } else if (t > 0){
      // LSTM1(t-1): X = [h0(t-1)=h0[pm] | h1(t-2)=h1[p]], writes h1[pm]
      const int u0 = (blk - 128) << 3;
      const int xb = tid >> 6, xcol = (tid & 63) << 2;
      float hold = prefetch_h(h1 + (p<<13), u0);
      float4 xr[8];
      #pragma unroll
      for (int c=0;c<4;++c) xr[c]   = ldg4_sc1(h0 + (pm<<13) + (xb<<10) + (c<<8) + xcol);
      #pragma unroll
      for (int c=0;c<4;++c) xr[4+c] = ldg4_sc1(h1 + (p<<13)  + (xb<<10) + (c<<8) + xcol);
      float dot = gemm_core<8>(sm, (const __half*)&sm[OFF_W], xr);
      if (tid < 256){
        int row32 = tid >> 3, gate = row32 >> 3, ul = row32 & 7;
        sm[OFF_EXG + tid] = dot + bl1[(gate<<10) + u0 + ul];
      }
      __syncthreads();
      if (tid < 64){
        float gi = sm[OFF_EXG + tid];
        float gf = sm[OFF_EXG + 64 + tid];
        float gg = sm[OFF_EXG + 128 + tid];
        float go = sm[OFF_EXG + 192 + tid];
        int ul2 = tid >> 3, b2 = tid & 7;
        int hi = (b2<<10) + u0 + ul2;
        float co = c1[hi];
        float cn = fsig_(gf)*co + fsig_(gi)*ftanh_(gg);
        float hn = fsig_(go)*ftanh_(cn);
        c1[hi] = 0.9f*cn + 0.1f*co;
        stg_sc1(h1 + (pm<<13) + hi, 0.9f*hn + 0.1f*hold);
      }
    }
    grid_barrier(bar, ++bt);

    // ---- Phase B(t): attn(t+1) [0-63] | cum/attw(t) [64-71] |
    //                  outstop(t-1) [72-152] | zero attc[p] [153-160] -------
    if (is_attn){
      if (t + 1 < TDz)
        attn_phase(sm, memory, mlen, pmT, qp, uw, cumg, attc, Sw, blk, t);
    } else if (blk < 72){
      const int b = blk - 64;
      float inv = 1.f / ldg_sc1(&Sw[(p<<3) + b]);
      for (int i = tid; i < TE; i += NT){
        float u = ldg_sc1(&uw[(p<<12) + (b<<9) + i]);
        float w = u * inv;
        d_out[97200 + ((size_t)b*TDz + t)*TE + i] = w;
        stg_sc1(&cumg[(p<<12) + (b<<9) + i],
                ldg_sc1(&cumg[(pm<<12) + (b<<9) + i]) + w);
      }
    } else if (blk < 153){
      if (t > 0)
        outstop_wave((blk-72)*8 + (tid>>6), t-1,
                     feat_W, stop_W, stop_b, h1 + (pm<<13), attcn + (pm<<12), d_out);
    } else if (blk < 161){
      // zero attc[p] (next accumulated by attn(t+2) in B(t+1))
      stg_sc1(&attc[(p<<12) + ((blk-153)<<9) + tid], 0.f);
    }
    grid_barrier(bar, ++bt);
  }

  // ---- epilogue: A(150) = LSTM1(149), then outstop(149). ------------------
  // t=150: pm-of-(t-1): h0(149) parity 1, h1(148) parity 0; writes h1[1].
  if (!is_l){
    const int u0 = (blk - 128) << 3;
    const int xb = tid >> 6, xcol = (tid & 63) << 2;
    float hold = prefetch_h(h1 + (0<<13), u0);
    float4 xr[8];
    #pragma unroll
    for (int c=0;c<4;++c) xr[c]   = ldg4_sc1(h0 + (1<<13) + (xb<<10) + (c<<8) + xcol);
    #pragma unroll
    for (int c=0;c<4;++c) xr[4+c] = ldg4_sc1(h1 + (0<<13) + (xb<<10) + (c<<8) + xcol);
    float dot = gemm_core<8>(sm, (const __half*)&sm[OFF_W], xr);
    if (tid < 256){
      int row32 = tid >> 3, gate = row32 >> 3, ul = row32 & 7;
      sm[OFF_EXG + tid] = dot + bl1[(gate<<10) + u0 + ul];
    }
    __syncthreads();
    if (tid < 64){
      float gi = sm[OFF_EXG + tid];
      float gf = sm[OFF_EXG + 64 + tid];
      float gg = sm[OFF_EXG + 128 + tid];
      float go = sm[OFF_EXG + 192 + tid];
      int ul2 = tid >> 3, b2 = tid & 7;
      int hi = (b2<<10) + u0 + ul2;
      float co = c1[hi];
      float cn = fsig_(gf)*co + fsig_(gi)*ftanh_(gg);
      float hn = fsig_(go)*ftanh_(cn);
      stg_sc1(h1 + (1<<13) + hi, 0.9f*hn + 0.1f*hold);
    }
  }
  grid_barrier(bar, ++bt);
  if (blk >= 72 && blk < 153)
    outstop_wave((blk-72)*8 + (tid>>6), TDz-1,
                 feat_W, stop_W, stop_b, h1 + (1<<13), attcn + (1<<12), d_out);
}

extern "C" void kernel_launch(void* const* d_in, const int* in_sizes, int n_in,
                              void* d_out, int out_size, void* d_ws, size_t ws_size,
                              hipStream_t stream)
{
  (void)in_sizes; (void)n_in; (void)out_size; (void)ws_size;
  (void)hipMemsetAsync((char*)d_ws + (size_t)OF_BAR*4, 0, 18432, stream);
  dec_kernel<<<dim3(NB), dim3(NT), 0, stream>>>(
    (const float*)d_in[0],  (const int*)d_in[1],   (const float*)d_in[2],
    (const float*)d_in[3],  (const float*)d_in[4],  (const float*)d_in[5],
    (const float*)d_in[6],  (const float*)d_in[7],  (const float*)d_in[8],
    (const float*)d_in[9],  (const float*)d_in[10], (const float*)d_in[11], (const float*)d_in[12],
    (const float*)d_in[13], (const float*)d_in[14], (const float*)d_in[15],
    (const float*)d_in[16], (const float*)d_in[17], (const float*)d_in[18],
    (const float*)d_in[19], (const float*)d_in[20], (const float*)d_in[21],
    (float*)d_out, (float*)d_ws);
}

// Round 8
// 4777.094 us; speedup vs baseline: 1.3462x; 1.3462x over previous
//
#include <hip/hip_runtime.h>
#include <hip/hip_fp16.h>
#include <cstdint>
#include <cstddef>

// ---------------------------------------------------------------------------
// Tacotron2-style decoder, persistent kernel. 256 blocks x 512 threads,
// 1 block/CU (150KB LDS). All five weight matrices live in LDS as fp16 for
// the whole kernel. 3 phases per step; cross-block state via sc1 (LLC).
// r8 = r4 (5175us) + two P1-shortening changes:
//  (1) attention spread 64->128 blocks (32 positions each; r2-validated
//      internals); blocks 64-127's previously-idle P1 now attends.
//  (2) gh0 tail rows 3968-4095 computed inline by the 128 LSTM1 blocks in
//      P3 (1 row each, reusing their h0 loads) -- frees blocks 64-67,
//      deletes the streamed-fp32 GEMM.
// Roles: blk 0-127 : P1 attn(32pos) | P2 LSTM0 | P3 gh0 tile / Wq (Wi0+Wh0/Wq)
//        blk 128-255: P1 gh1       | P2 attw/outstop | P3 LSTM1 + gh0 tail row
// ---------------------------------------------------------------------------

#define NB 256
#define NT 512

#define Bz   8
#define TE   512
#define DINz 512
#define TDz  150
#define ODz  80
#define DRz  1024
#define PREz 256
#define ATz  128
#define LOCz 32
#define KFz  31

// workspace offsets (floats)
#define OF_P    0            // prenet [1200][256]
#define OF_PM   307200       // pmT [128 blk][128 a][32 il]
#define OF_Q    831488       // q [128a][8b]
#define OF_U    832512       // u [8][512]
#define OF_CUM  836608       // att_cum [8][512]
#define OF_ATTC 840704       // unnormalized att_c [2][8][512]
#define OF_S    848896       // S [2][8]
#define OF_INVS 848912       // 1/S [2][8]
#define OF_H0   848928
#define OF_C0   857120
#define OF_H1   865312
#define OF_C1   873504
#define OF_GH0  881696       // gh0 [4096][8]
#define OF_GH1  914464       // gh1 [4096][8]
#define OF_BAR  947232       // 4608 ints: slots[256*16] | epochs@4096+grp*16

// shared-memory offsets (floats)
#define OFF_X0   0           // X chunk buffer A [8][256]
#define OFF_X1   2048        // X chunk buffer B
#define OFF_EX   4096        // reduce exchange [256]
#define OFF_EXG  4352        // gate exchange [256]
#define OFF_CW   4608        // attn cum window [96] (blk<128, P1 only)
#define OFF_QS   4736        // attn q slab [128]
#define OFF_PART 4864        // attn partials [32 il][16 ag]
#define OFF_UU   5376        // attn u stage [32]
#define OFF_F    5632        // attn F = W_loc@filters [128*31]
#define OFF_V    9600        // attn v [128]
#define OFF_WA   9728        // blk<128: fp16 Wi0 tile 32x768   (12288 f)
#define OFF_WB   22016       // blk<128: fp16 Wh0/Wq tile 32x1024 (16384 f)
#define OFF_WG1  4608        // blk>=128: fp16 Wh1 tile 32x1024 (16384 f)
#define OFF_WG2  20992       // blk>=128: fp16 Wi1 tile 32x1024 (16384 f)
#define SM_TOTF  38400       // 153600 B

#define AG __HIP_MEMORY_SCOPE_AGENT

__device__ __forceinline__ float ldg_sc1(const float* p){
  return __hip_atomic_load(p, __ATOMIC_RELAXED, AG);
}
__device__ __forceinline__ void stg_sc1(float* p, float v){
  __hip_atomic_store(p, v, __ATOMIC_RELAXED, AG);
}
__device__ __forceinline__ float4 ldg4_sc1(const float* p){
  float4 r; r.x=ldg_sc1(p); r.y=ldg_sc1(p+1); r.z=ldg_sc1(p+2); r.w=ldg_sc1(p+3);
  return r;
}
__device__ __forceinline__ float fsig_(float x){ return 1.f/(1.f + __expf(-x)); }
__device__ __forceinline__ float ftanh_(float x){
  x = fminf(10.f, fmaxf(-10.f, x));
  float e = __expf(2.f*x);
  return (e - 1.f) / (e + 1.f);
}

// -------- store/scan grid barrier (r4 variant, measured 5175us) ------------
__device__ __forceinline__ void grid_barrier(int* bar, int target){
  asm volatile("s_waitcnt vmcnt(0) lgkmcnt(0)" ::: "memory");
  __syncthreads();
  const int tid = threadIdx.x;
  if (tid == 0)
    __hip_atomic_store(bar + (blockIdx.x << 4), target, __ATOMIC_RELAXED, AG);
  if (blockIdx.x == 255){
    for (;;){
      int ok = 1;
      if (tid < 256)
        ok = (__hip_atomic_load(bar + (tid << 4), __ATOMIC_RELAXED, AG) >= target);
      if (__syncthreads_and(ok)) break;
    }
    if (tid < 16)
      __hip_atomic_store(bar + 4096 + (tid << 4), target, __ATOMIC_RELAXED, AG);
  }
  if (tid == 0){
    int* ep = bar + 4096 + ((blockIdx.x >> 4) << 4);
    while (__hip_atomic_load(ep, __ATOMIC_RELAXED, AG) < target)
      __builtin_amdgcn_s_sleep(1);
  }
  __syncthreads();
}
// heavy barrier (after init only)
__device__ __forceinline__ void grid_barrier_heavy(int* bar, int target){
  asm volatile("s_waitcnt vmcnt(0) lgkmcnt(0)" ::: "memory");
  __syncthreads();
  const int tid = threadIdx.x;
  if (tid == 0)
    __builtin_amdgcn_fence(__ATOMIC_RELEASE, "agent");
  __syncthreads();
  if (tid == 0)
    __hip_atomic_store(bar + (blockIdx.x << 4), target, __ATOMIC_RELAXED, AG);
  if (blockIdx.x == 255){
    for (;;){
      int ok = 1;
      if (tid < 256)
        ok = (__hip_atomic_load(bar + (tid << 4), __ATOMIC_RELAXED, AG) >= target);
      if (__syncthreads_and(ok)) break;
    }
    if (tid < 16)
      __hip_atomic_store(bar + 4096 + (tid << 4), target, __ATOMIC_RELAXED, AG);
  }
  if (tid == 0){
    int* ep = bar + 4096 + ((blockIdx.x >> 4) << 4);
    while (__hip_atomic_load(ep, __ATOMIC_RELAXED, AG) < target)
      __builtin_amdgcn_s_sleep(1);
    __builtin_amdgcn_fence(__ATOMIC_ACQUIRE, "agent");
  }
  __syncthreads();
}

// init: load 32xK fp32 tile from global -> fp16 LDS (optionally gate-mapped)
template<int K, bool GM>
__device__ void load_wtile(float* dstf, const float* __restrict__ W, int base){
  __half* dst = (__half*)dstf;
  constexpr int KV = K >> 2;
  constexpr int NV = 32 * KV;
  for (int idx = threadIdx.x; idx < NV; idx += NT){
    int r = idx / KV;
    int c = (idx - r*KV) << 2;
    int grow = GM ? (((r>>3)<<10) + base + (r&7)) : (base + r);
    float4 w = *(const float4*)(W + (size_t)grow*K + c);
    __half* d = dst + (size_t)r*K + c;
    d[0] = __float2half_rn(w.x);
    d[1] = __float2half_rn(w.y);
    d[2] = __float2half_rn(w.z);
    d[3] = __float2half_rn(w.w);
  }
}

// reduce 32 k-slice partials -> dot for tid<256 (row = tid>>3, b = tid&7)
__device__ __forceinline__ float reduce_dot(float* sm, float (&acc)[2][8]){
  const int tid = threadIdx.x;
  const int s = tid & 31, pos = tid >> 5;
  #pragma unroll
  for (int i=0;i<2;++i){
    #pragma unroll
    for (int b=0;b<8;++b){
      float v = acc[i][b];
      v += __shfl_xor(v, 16, 64);
      v += __shfl_xor(v,  8, 64);
      v += __shfl_xor(v,  4, 64);
      v += __shfl_xor(v,  2, 64);
      v += __shfl_xor(v,  1, 64);
      acc[i][b] = v;
    }
  }
  if (s == 0){
    #pragma unroll
    for (int i=0;i<2;++i)
      #pragma unroll
      for (int b=0;b<8;++b)
        sm[OFF_EX + ((((pos<<1)+i)<<3) | b)] = acc[i][b];
  }
  __syncthreads();
  return (tid < 256) ? sm[OFF_EX + tid] : 0.f;
}

// GEMM tile: out[row 0..31][b 0..7] = sum_k Wlds[row][k] * X[b][k]
template<int K, int XMODE>
__device__ float gemm32x8_lds(float* sm, const __half* __restrict__ wlds,
                              const float* __restrict__ xsrc,
                              const float* __restrict__ attc_cur,
                              const float* __restrict__ S_cur,
                              const float* __restrict__ Pt)
{
  constexpr int NCH = K >> 8;
  const int tid = threadIdx.x;
  const int s = tid & 31, pos = tid >> 5;
  float acc[2][8];
  #pragma unroll
  for (int i=0;i<2;++i)
    #pragma unroll
    for (int b=0;b<8;++b) acc[i][b] = 0.f;

  const int xb = tid >> 6, xcol = (tid & 63) << 2;
  float4 xreg[NCH];
  if constexpr (XMODE == 0){
    #pragma unroll
    for (int ch=0; ch<NCH; ++ch)
      xreg[ch] = ldg4_sc1(xsrc + (size_t)xb*K + (ch<<8) + xcol);
  } else {
    float xsc = 1.f / ldg_sc1(S_cur + xb);
    #pragma unroll
    for (int ch=0; ch<2; ++ch){
      float4 v = ldg4_sc1(attc_cur + (xb<<9) + (ch<<8) + xcol);
      v.x*=xsc; v.y*=xsc; v.z*=xsc; v.w*=xsc;
      xreg[ch] = v;
    }
    xreg[2] = *(const float4*)(Pt + (xb<<8) + xcol);
  }
  *(float4*)&sm[OFF_X0 + (xb<<8) + xcol] = xreg[0];
  __syncthreads();
  #pragma unroll
  for (int ch=0; ch<NCH; ++ch){
    if (ch+1 < NCH)
      *(float4*)&sm[(((ch+1)&1) ? OFF_X1 : OFF_X0) + (xb<<8) + xcol] = xreg[(ch+1 < NCH) ? ch+1 : 0];
    const float* xbase = &sm[((ch&1) ? OFF_X1 : OFF_X0)];
    const __half* wch = wlds + (ch<<8);
    #pragma unroll
    for (int j=0;j<2;++j){
      const int k = (j<<7) + (s<<2);
      float4 xv[8];
      #pragma unroll
      for (int b=0;b<8;++b) xv[b] = *(const float4*)&xbase[(b<<8) + k];
      #pragma unroll
      for (int i=0;i<2;++i){
        const int row = (pos<<1) + i;
        uint2 w2 = *(const uint2*)&wch[(size_t)row*K + k];
        __half2 ha = *reinterpret_cast<const __half2*>(&w2.x);
        __half2 hb = *reinterpret_cast<const __half2*>(&w2.y);
        float2 fa = __half22float2(ha);
        float2 fb = __half22float2(hb);
        #pragma unroll
        for (int b=0;b<8;++b){
          acc[i][b] = fmaf(fa.x, xv[b].x, acc[i][b]);
          acc[i][b] = fmaf(fa.y, xv[b].y, acc[i][b]);
          acc[i][b] = fmaf(fb.x, xv[b].z, acc[i][b]);
          acc[i][b] = fmaf(fb.y, xv[b].w, acc[i][b]);
        }
      }
    }
    __syncthreads();
  }
  return reduce_dot(sm, acc);
}

// issue the epilogue's LLC loads BEFORE the gemm so their latency hides
__device__ __forceinline__ float prefetch_gh(const float* gh, int u0){
  const int tid = threadIdx.x;
  if (tid >= 256) return 0.f;
  int row32 = tid >> 3, b = tid & 7;
  int gate = row32 >> 3, ul = row32 & 7;
  return ldg_sc1(&gh[(((gate<<10) + u0 + ul)<<3) + b]);
}
__device__ __forceinline__ float prefetch_h(const float* h, int u0){
  const int tid = threadIdx.x;
  if (tid >= 64) return 0.f;
  return ldg_sc1(&h[((tid&7)<<10) + u0 + (tid>>3)]);
}

__device__ void lstm_epilogue(float* sm, float dot, float ghb,
                              const float* __restrict__ bias, float hold,
                              float* __restrict__ h, float* __restrict__ c, int u0)
{
  const int tid = threadIdx.x;
  if (tid < 256){
    int row32 = tid >> 3;
    int gate = row32 >> 3, ul = row32 & 7;
    sm[OFF_EXG + tid] = dot + bias[(gate<<10) + u0 + ul] + ghb;
  }
  __syncthreads();
  if (tid < 64){
    float gi = sm[OFF_EXG + tid];
    float gf = sm[OFF_EXG + 64 + tid];
    float gg = sm[OFF_EXG + 128 + tid];
    float go = sm[OFF_EXG + 192 + tid];
    int ul2 = tid >> 3, b2 = tid & 7;
    int hi = (b2<<10) + u0 + ul2;
    float co = c[hi];               // block-private: cached
    float cn = fsig_(gf)*co + fsig_(gi)*ftanh_(gg);
    float hn = fsig_(go)*ftanh_(cn);
    c[hi] = 0.9f*cn + 0.1f*co;
    stg_sc1(&h[hi], 0.9f*hn + 0.1f*hold);
  }
}

// one output row per wave: rr = b*81 + r (r==80 -> stop)
__device__ void outstop_wave(int rr, int tp, int par,
    const float* __restrict__ feat_W, const float* __restrict__ stop_W,
    const float* __restrict__ stop_b, const float* __restrict__ h1,
    const float* __restrict__ attc, const float* __restrict__ iSw,
    float* __restrict__ d_out)
{
  if (rr >= 648) return;
  int b = rr / 81, r = rr - 81*b;
  int lane = threadIdx.x & 63;
  const float4* Wr = (const float4*)((r < 80) ? (feat_W + (size_t)r*1536) : stop_W);
  float inv = ldg_sc1(iSw + (par<<3) + b);
  float acc = 0.f, acc2 = 0.f;
  #pragma unroll
  for (int j=0;j<4;++j){
    int p = lane + (j<<6);
    float4 w = Wr[p], x = ldg4_sc1(h1 + (b<<10) + (p<<2));
    acc = fmaf(w.x,x.x, fmaf(w.y,x.y, fmaf(w.z,x.z, fmaf(w.w,x.w, acc))));
  }
  #pragma unroll
  for (int j=4;j<6;++j){
    int p = lane + (j<<6);
    float4 w = Wr[p], x = ldg4_sc1(attc + (par<<12) + (b<<9) + ((p-256)<<2));
    acc2 = fmaf(w.x,x.x, fmaf(w.y,x.y, fmaf(w.z,x.z, fmaf(w.w,x.w, acc2))));
  }
  acc += acc2 * inv;
  acc += __shfl_down(acc, 32, 64);
  acc += __shfl_down(acc, 16, 64);
  acc += __shfl_down(acc,  8, 64);
  acc += __shfl_down(acc,  4, 64);
  acc += __shfl_down(acc,  2, 64);
  acc += __shfl_down(acc,  1, 64);
  if (lane == 0){
    if (r < 80) d_out[((size_t)b*TDz + tp)*ODz + r] = acc;
    else        d_out[96000 + (size_t)b*TDz + tp] = acc + stop_b[0];
  }
}

extern "C" __global__ void __launch_bounds__(NT, 1) dec_kernel(
  const float* __restrict__ memory, const int* __restrict__ mlen, const float* __restrict__ targets,
  const float* __restrict__ W_mem, const float* __restrict__ W_q, const float* __restrict__ W_loc,
  const float* __restrict__ loc_f, const float* __restrict__ attn_v, const float* __restrict__ attn_b,
  const float* __restrict__ pre_W1, const float* __restrict__ pre_b1,
  const float* __restrict__ pre_W2, const float* __restrict__ pre_b2,
  const float* __restrict__ Wi0, const float* __restrict__ Wh0, const float* __restrict__ bl0,
  const float* __restrict__ Wi1, const float* __restrict__ Wh1, const float* __restrict__ bl1,
  const float* __restrict__ feat_W, const float* __restrict__ stop_W, const float* __restrict__ stop_b,
  float* __restrict__ d_out, float* __restrict__ ws)
{
  __shared__ float sm[SM_TOTF];
  const int blk = blockIdx.x, tid = threadIdx.x;

  float* Pw   = ws + OF_P;
  float* pmT  = ws + OF_PM;
  float* qw   = ws + OF_Q;
  float* uw   = ws + OF_U;
  float* cum  = ws + OF_CUM;
  float* attc = ws + OF_ATTC;
  float* Sw   = ws + OF_S;
  float* iSw  = ws + OF_INVS;
  float* h0 = ws + OF_H0; float* c0 = ws + OF_C0;
  float* h1 = ws + OF_H1; float* c1 = ws + OF_C1;
  float* gh0 = ws + OF_GH0; float* gh1 = ws + OF_GH1;
  int* bar = (int*)(ws + OF_BAR);
  int bt = 0;

  const bool is_attn = (blk < 128);
  const int ab  = blk >> 4;          // attention batch (blk<128)
  const int ai0 = (blk & 15) << 5;   // attention base position (32-wide)
  const int il  = tid & 31;          // position within slice
  const int ag  = tid >> 5;          // feature group (0..15)

  // ------------------------- INIT (every launch) ---------------------------
  {
    const int gs = NB*NT;
    const int gid = blk*NT + tid;
    for (int i = gid; i < 98304; i += gs) h0[i] = 0.f;    // h0,c0,h1,c1,gh0,gh1
    for (int i = gid; i < 1024;  i += gs) qw[i]  = 0.f;
    for (int i = gid; i < 4096;  i += gs) cum[i] = 0.f;
    for (int i = gid; i < 8192;  i += gs) attc[i] = 0.f;
    if (gid < 32) Sw[gid] = 0.f;                          // S + invS

    // persistent weights -> LDS fp16
    if (blk < 124){
      load_wtile<768, true >(&sm[OFF_WA], Wi0, blk<<3);
      load_wtile<1024,false>(&sm[OFF_WB], Wh0, blk<<5);
    } else if (blk < 128){
      load_wtile<768, true >(&sm[OFF_WA], Wi0, blk<<3);
      load_wtile<1024,false>(&sm[OFF_WB], W_q, (blk-124)<<5);
    } else {
      load_wtile<1024,false>(&sm[OFF_WG1], Wh1, (blk-128)<<5);
      load_wtile<1024,true >(&sm[OFF_WG2], Wi1, (blk-128)<<3);
    }

    if (is_attn){
      // pmT[a][il] = mem[ab, ai0+il, :] . W_mem[a,:] + attn_b[a]
      // 32-position slice; staging sm[0..4127] (below all slab/W regions)
      float pacc[8];
      #pragma unroll
      for (int j=0;j<8;++j) pacc[j] = 0.f;
      for (int dc=0; dc<4; ++dc){
        for (int idx = tid; idx < 4096; idx += NT){
          int r = idx >> 7, d = idx & 127;
          sm[r*129 + d] = memory[(size_t)((ab<<9)+ai0+r)*DINz + (dc<<7) + d];
        }
        __syncthreads();
        #pragma unroll
        for (int j=0;j<8;++j){
          int a = (ag<<3) + j;
          const float* wr = W_mem + (size_t)a*DINz + (dc<<7);
          const float* mr = &sm[il*129];
          float acc = 0.f;
          for (int d=0; d<128; d+=4){
            acc = fmaf(mr[d  ], wr[d  ], acc);
            acc = fmaf(mr[d+1], wr[d+1], acc);
            acc = fmaf(mr[d+2], wr[d+2], acc);
            acc = fmaf(mr[d+3], wr[d+3], acc);
          }
          pacc[j] += acc;
        }
        __syncthreads();
      }
      #pragma unroll
      for (int j=0;j<8;++j){
        int a = (ag<<3) + j;
        pmT[((size_t)blk<<12) + (a<<5) + il] = pacc[j] + attn_b[a];
      }
      // persistent slabs: F = W_loc @ filters, v
      for (int idx = tid; idx < ATz*KFz; idx += NT){
        int a = idx / KFz, k = idx - a*KFz;
        float s2 = 0.f;
        #pragma unroll
        for (int c2=0;c2<LOCz;++c2) s2 = fmaf(W_loc[(a<<5)+c2], loc_f[c2*KFz+k], s2);
        sm[OFF_F + idx] = s2;
      }
      if (tid < 128) sm[OFF_V + tid] = attn_v[tid];
      __syncthreads();
    }

    // prenet for all (t,b) pairs; scratch in sm[0..1023]
    const int th = tid >> 8, t2 = tid & 255, base = th << 9;
    for (int it=0; it<3; ++it){
      int pp = (blk<<1) + th + (it<<9);
      bool act = pp < 1200;
      if (act && t2 < ODz){
        int tt = pp >> 3, bb = pp & 7;
        sm[base + t2] = (tt==0) ? 0.f : targets[((size_t)bb*TDz + (tt-1))*ODz + t2];
      }
      __syncthreads();
      if (act){
        float a1 = pre_b1[t2];
        for (int k=0;k<ODz;++k) a1 = fmaf(pre_W1[t2*ODz+k], sm[base+k], a1);
        sm[base + 128 + t2] = fmaxf(a1, 0.f);
      }
      __syncthreads();
      if (act){
        float a2 = pre_b2[t2];
        for (int k=0;k<PREz;++k) a2 = fmaf(pre_W2[(t2<<8)+k], sm[base+128+k], a2);
        Pw[((size_t)pp<<8) + t2] = fmaxf(a2, 0.f);
      }
      __syncthreads();
    }
  }
  grid_barrier_heavy(bar, ++bt);

  // ------------------------------ MAIN LOOP (3 phases) ---------------------
  for (int t = 0; t < TDz; ++t){
    const int cur = t & 1, prv = cur ^ 1;

    // ---- P1: attention (0-127, 32 pos each) | gh1 (128-255) ---------------
    if (is_attn){
      if (tid < 62){
        int gi = ai0 - 15 + tid;
        sm[OFF_CW + tid] = (gi >= 0 && gi < TE) ? ldg_sc1(&cum[(ab<<9)+gi]) : 0.f;
      }
      if (tid < 128) sm[OFF_QS + tid] = ldg_sc1(&qw[(tid<<3) + ab]);
      __syncthreads();
      float part = 0.f;
      #pragma unroll
      for (int j=0;j<8;++j){
        int a = (ag<<3) + j;
        const float* fb = &sm[OFF_F + a*KFz];
        float conv = 0.f;
        #pragma unroll
        for (int k=0;k<KFz;++k) conv = fmaf(fb[k], sm[OFF_CW + il + k], conv);
        float pv = pmT[((size_t)blk<<12) + (a<<5) + il];
        part = fmaf(sm[OFF_V + a], ftanh_(pv + sm[OFF_QS + a] + conv), part);
      }
      sm[OFF_PART + (il<<4) + ag] = part;
      __syncthreads();
      if (tid < 32){
        float e = 0.f;
        #pragma unroll
        for (int k=0;k<16;++k) e += sm[OFF_PART + (tid<<4) + k];
        int gi = ai0 + tid;
        float uu = (gi < mlen[ab]) ? __expf(e) : 0.f;
        stg_sc1(&uw[(ab<<9)+gi], uu);
        sm[OFF_UU + tid] = uu;
      }
      __syncthreads();
      if (tid == 0){
        float ssum = 0.f;
        #pragma unroll
        for (int k=0;k<32;++k) ssum += sm[OFF_UU + k];
        atomicAdd(&Sw[(cur<<3)+ab], ssum);
      }
      {
        float acc = 0.f;
        const float* mrow = memory + (size_t)((ab<<9)+ai0)*DINz + tid;
        #pragma unroll 8
        for (int i=0;i<32;++i)
          acc = fmaf(sm[OFF_UU + i], mrow[(size_t)i*DINz], acc);
        atomicAdd(&attc[(cur<<12) + (ab<<9) + tid], acc);
      }
    } else {
      const int tile = blk - 128;
      float dot = gemm32x8_lds<1024,0>(sm, (const __half*)&sm[OFF_WG1], h1,
                                       nullptr, nullptr, nullptr);
      if (tid < 256) stg_sc1(&gh1[(tile<<8) + tid], dot);
    }
    grid_barrier(bar, ++bt);

    // ---- P2: LSTM0 (0-127) | attw/cum (128-135) | outstop t-1 (136-216) ---
    if (blk < 128){
      const int u0 = blk << 3;
      float ghb  = prefetch_gh(gh0, u0);
      float hold = prefetch_h(h0, u0);
      float dot = gemm32x8_lds<768,1>(sm, (const __half*)&sm[OFF_WA], nullptr,
                                      attc + (cur<<12), Sw + (cur<<3),
                                      Pw + ((size_t)t<<11));
      lstm_epilogue(sm, dot, ghb, bl0, hold, h0, c0, u0);
    } else if (blk < 136){
      const int b = blk - 128;
      float Sv = __hip_atomic_load(&Sw[(cur<<3)+b], __ATOMIC_RELAXED, AG);
      float inv = 1.f / Sv;
      if (tid == 0) stg_sc1(&iSw[(cur<<3)+b], inv);
      for (int i = tid; i < TE; i += NT){
        float u = ldg_sc1(&uw[(b<<9)+i]);
        float w = u * inv;
        d_out[97200 + ((size_t)b*TDz + t)*TE + i] = w;
        stg_sc1(&cum[(b<<9)+i], ldg_sc1(&cum[(b<<9)+i]) + w);
      }
    } else if (blk < 217){
      if (t > 0)
        outstop_wave((blk-136)*8 + (tid>>6), t-1, prv,
                     feat_W, stop_W, stop_b, h1, attc, iSw, d_out);
    }
    grid_barrier(bar, ++bt);

    // ---- P3: gh0 0-123 | Wq + zero duties (124-127) |
    //          LSTM1 + gh0 tail row (128-255) -----------------------------
    if (blk < 124){
      float dot = gemm32x8_lds<1024,0>(sm, (const __half*)&sm[OFF_WB], h0,
                                       nullptr, nullptr, nullptr);
      if (tid < 256) stg_sc1(&gh0[(blk<<8) + tid], dot);
    } else if (blk < 128){
      const int rt = blk - 124;
      float dot = gemm32x8_lds<1024,0>(sm, (const __half*)&sm[OFF_WB], h0,
                                       nullptr, nullptr, nullptr);
      if (tid < 256) stg_sc1(&qw[(rt<<8) + tid], dot);
      const int zbase = (prv<<12) + (rt<<10);
      for (int i = tid; i < 1024; i += NT) stg_sc1(&attc[zbase + i], 0.f);
      if (rt == 0 && tid < 8) stg_sc1(&Sw[(prv<<3)+tid], 0.f);
    } else {
      const int u0 = (blk - 128) << 3;
      const int blkL = blk - 128;
      // inline gh0 tail: row 3968+blkL = Wh0 row . h0[b] for b=0..7.
      // Wave w (= batch w) reduces its 64 lanes' partials; W row is L2-hot.
      {
        const int xb = tid >> 6, xcol = (tid & 63) << 2;
        const float* wr = Wh0 + (size_t)(3968 + blkL)*1024;
        float tp_ = 0.f;
        #pragma unroll
        for (int c=0;c<4;++c){
          float4 w = *(const float4*)(wr + (c<<8) + xcol);
          float4 x = ldg4_sc1(h0 + (xb<<10) + (c<<8) + xcol);
          tp_ = fmaf(w.x,x.x, fmaf(w.y,x.y, fmaf(w.z,x.z, fmaf(w.w,x.w, tp_))));
        }
        tp_ += __shfl_down(tp_, 32, 64);
        tp_ += __shfl_down(tp_, 16, 64);
        tp_ += __shfl_down(tp_,  8, 64);
        tp_ += __shfl_down(tp_,  4, 64);
        tp_ += __shfl_down(tp_,  2, 64);
        tp_ += __shfl_down(tp_,  1, 64);
        if ((tid & 63) == 0) stg_sc1(&gh0[((3968 + blkL)<<3) + xb], tp_);
      }
      float ghb  = prefetch_gh(gh1, u0);
      float hold = prefetch_h(h1, u0);
      float dot = gemm32x8_lds<1024,0>(sm, (const __half*)&sm[OFF_WG2], h0,
                                       nullptr, nullptr, nullptr);
      lstm_epilogue(sm, dot, ghb, bl1, hold, h1, c1, u0);
    }
    grid_barrier(bar, ++bt);
  }

  // final out/stop for t = 149 (parity 1)
  if (blk >= 136 && blk < 217)
    outstop_wave((blk-136)*8 + (tid>>6), TDz-1, 1,
                 feat_W, stop_W, stop_b, h1, attc, iSw, d_out);
}

extern "C" void kernel_launch(void* const* d_in, const int* in_sizes, int n_in,
                              void* d_out, int out_size, void* d_ws, size_t ws_size,
                              hipStream_t stream)
{
  (void)in_sizes; (void)n_in; (void)out_size; (void)ws_size;
  (void)hipMemsetAsync((char*)d_ws + (size_t)OF_BAR*4, 0, 18432, stream);
  dec_kernel<<<dim3(NB), dim3(NT), 0, stream>>>(
    (const float*)d_in[0],  (const int*)d_in[1],   (const float*)d_in[2],
    (const float*)d_in[3],  (const float*)d_in[4],  (const float*)d_in[5],
    (const float*)d_in[6],  (const float*)d_in[7],  (const float*)d_in[8],
    (const float*)d_in[9],  (const float*)d_in[10], (const float*)d_in[11], (const float*)d_in[12],
    (const float*)d_in[13], (const float*)d_in[14], (const float*)d_in[15],
    (const float*)d_in[16], (const float*)d_in[17], (const float*)d_in[18],
    (const float*)d_in[19], (const float*)d_in[20], (const float*)d_in[21],
    (float*)d_out, (float*)d_ws);
}

// Round 10
// 4766.752 us; speedup vs baseline: 1.3491x; 1.0022x over previous
//
#include <hip/hip_runtime.h>
#include <hip/hip_fp16.h>
#include <cstdint>
#include <cstddef>

// ---------------------------------------------------------------------------
// Tacotron2-style decoder, persistent kernel. 256 blocks x 512 threads,
// 1 block/CU (150KB LDS). All five weight matrices live in LDS as fp16.
// 3 phases per step; cross-block state via sc1 (LLC).
// r10 = r9 resubmission (container acquisition failed; kernel unchanged):
//  (1) attn PART tile stride 16->17 (16-way LDS bank conflict fix)
//  (2) P2 GEMM operands (gh0, hold, Pw chunk, h0 X-chunks) prefetched at P1
//      start on blocks 0-127 and carried in registers through attention
//  (3) P1-end barrier is arrive-only for blocks 136-255 (outstop reads only
//      P2/P3(t-1)-era data; nothing in P1 writes it) -- outstop overlaps P1.
//      Scanner block 255 still scans; full P2-end barrier restores order.
// Roles: blk 0-127 : P1 attn(32pos)+P2-prefetch | P2 LSTM0 | P3 gh0/Wq
//        blk 128-255: P1 gh1 | P2 attw(128-135)/outstop(136-216) | P3 LSTM1+tail
// ---------------------------------------------------------------------------

#define NB 256
#define NT 512

#define Bz   8
#define TE   512
#define DINz 512
#define TDz  150
#define ODz  80
#define DRz  1024
#define PREz 256
#define ATz  128
#define LOCz 32
#define KFz  31

// workspace offsets (floats)
#define OF_P    0            // prenet [1200][256]
#define OF_PM   307200       // pmT [128 blk][128 a][32 il]
#define OF_Q    831488       // q [128a][8b]
#define OF_U    832512       // u [8][512]
#define OF_CUM  836608       // att_cum [8][512]
#define OF_ATTC 840704       // unnormalized att_c [2][8][512]
#define OF_S    848896       // S [2][8]
#define OF_INVS 848912       // 1/S [2][8]
#define OF_H0   848928
#define OF_C0   857120
#define OF_H1   865312
#define OF_C1   873504
#define OF_GH0  881696       // gh0 [4096][8]
#define OF_GH1  914464       // gh1 [4096][8]
#define OF_BAR  947232       // 4608 ints: slots[256*16] | epochs@4096+grp*16

// shared-memory offsets (floats)
#define OFF_X0   0           // X chunk buffer A [8][256]
#define OFF_X1   2048        // X chunk buffer B
#define OFF_EX   4096        // reduce exchange [256]
#define OFF_EXG  4352        // gate exchange [256]
#define OFF_CW   4608        // attn cum window [96] (blk<128, P1 only)
#define OFF_QS   4736        // attn q slab [128]
#define OFF_PART 4864        // attn partials [32 il][17] (stride 17: no conflicts)
#define OFF_UU   5408        // attn u stage [32]
#define OFF_F    5632        // attn F = W_loc@filters [128*31]
#define OFF_V    9600        // attn v [128]
#define OFF_WA   9728        // blk<128: fp16 Wi0 tile 32x768   (12288 f)
#define OFF_WB   22016       // blk<128: fp16 Wh0/Wq tile 32x1024 (16384 f)
#define OFF_WG1  4608        // blk>=128: fp16 Wh1 tile 32x1024 (16384 f)
#define OFF_WG2  20992       // blk>=128: fp16 Wi1 tile 32x1024 (16384 f)
#define SM_TOTF  38400       // 153600 B

#define AG __HIP_MEMORY_SCOPE_AGENT

__device__ __forceinline__ float ldg_sc1(const float* p){
  return __hip_atomic_load(p, __ATOMIC_RELAXED, AG);
}
__device__ __forceinline__ void stg_sc1(float* p, float v){
  __hip_atomic_store(p, v, __ATOMIC_RELAXED, AG);
}
__device__ __forceinline__ float4 ldg4_sc1(const float* p){
  float4 r; r.x=ldg_sc1(p); r.y=ldg_sc1(p+1); r.z=ldg_sc1(p+2); r.w=ldg_sc1(p+3);
  return r;
}
__device__ __forceinline__ float fsig_(float x){ return 1.f/(1.f + __expf(-x)); }
__device__ __forceinline__ float ftanh_(float x){
  x = fminf(10.f, fmaxf(-10.f, x));
  float e = __expf(2.f*x);
  return (e - 1.f) / (e + 1.f);
}

// -------- store/scan grid barrier (r4 variant, measured) -------------------
__device__ __forceinline__ void grid_barrier(int* bar, int target){
  asm volatile("s_waitcnt vmcnt(0) lgkmcnt(0)" ::: "memory");
  __syncthreads();
  const int tid = threadIdx.x;
  if (tid == 0)
    __hip_atomic_store(bar + (blockIdx.x << 4), target, __ATOMIC_RELAXED, AG);
  if (blockIdx.x == 255){
    for (;;){
      int ok = 1;
      if (tid < 256)
        ok = (__hip_atomic_load(bar + (tid << 4), __ATOMIC_RELAXED, AG) >= target);
      if (__syncthreads_and(ok)) break;
    }
    if (tid < 16)
      __hip_atomic_store(bar + 4096 + (tid << 4), target, __ATOMIC_RELAXED, AG);
  }
  if (tid == 0){
    int* ep = bar + 4096 + ((blockIdx.x >> 4) << 4);
    while (__hip_atomic_load(ep, __ATOMIC_RELAXED, AG) < target)
      __builtin_amdgcn_s_sleep(1);
  }
  __syncthreads();
}
// arrive-only: store arrival, do not wait (caller's next full barrier orders)
__device__ __forceinline__ void grid_barrier_arrive(int* bar, int target){
  asm volatile("s_waitcnt vmcnt(0) lgkmcnt(0)" ::: "memory");
  __syncthreads();
  if (threadIdx.x == 0)
    __hip_atomic_store(bar + (blockIdx.x << 4), target, __ATOMIC_RELAXED, AG);
}
// heavy barrier (after init only)
__device__ __forceinline__ void grid_barrier_heavy(int* bar, int target){
  asm volatile("s_waitcnt vmcnt(0) lgkmcnt(0)" ::: "memory");
  __syncthreads();
  const int tid = threadIdx.x;
  if (tid == 0)
    __builtin_amdgcn_fence(__ATOMIC_RELEASE, "agent");
  __syncthreads();
  if (tid == 0)
    __hip_atomic_store(bar + (blockIdx.x << 4), target, __ATOMIC_RELAXED, AG);
  if (blockIdx.x == 255){
    for (;;){
      int ok = 1;
      if (tid < 256)
        ok = (__hip_atomic_load(bar + (tid << 4), __ATOMIC_RELAXED, AG) >= target);
      if (__syncthreads_and(ok)) break;
    }
    if (tid < 16)
      __hip_atomic_store(bar + 4096 + (tid << 4), target, __ATOMIC_RELAXED, AG);
  }
  if (tid == 0){
    int* ep = bar + 4096 + ((blockIdx.x >> 4) << 4);
    while (__hip_atomic_load(ep, __ATOMIC_RELAXED, AG) < target)
      __builtin_amdgcn_s_sleep(1);
    __builtin_amdgcn_fence(__ATOMIC_ACQUIRE, "agent");
  }
  __syncthreads();
}

// init: load 32xK fp32 tile from global -> fp16 LDS (optionally gate-mapped)
template<int K, bool GM>
__device__ void load_wtile(float* dstf, const float* __restrict__ W, int base){
  __half* dst = (__half*)dstf;
  constexpr int KV = K >> 2;
  constexpr int NV = 32 * KV;
  for (int idx = threadIdx.x; idx < NV; idx += NT){
    int r = idx / KV;
    int c = (idx - r*KV) << 2;
    int grow = GM ? (((r>>3)<<10) + base + (r&7)) : (base + r);
    float4 w = *(const float4*)(W + (size_t)grow*K + c);
    __half* d = dst + (size_t)r*K + c;
    d[0] = __float2half_rn(w.x);
    d[1] = __float2half_rn(w.y);
    d[2] = __float2half_rn(w.z);
    d[3] = __float2half_rn(w.w);
  }
}

// reduce 32 k-slice partials -> dot for tid<256 (row = tid>>3, b = tid&7)
__device__ __forceinline__ float reduce_dot(float* sm, float (&acc)[2][8]){
  const int tid = threadIdx.x;
  const int s = tid & 31, pos = tid >> 5;
  #pragma unroll
  for (int i=0;i<2;++i){
    #pragma unroll
    for (int b=0;b<8;++b){
      float v = acc[i][b];
      v += __shfl_xor(v, 16, 64);
      v += __shfl_xor(v,  8, 64);
      v += __shfl_xor(v,  4, 64);
      v += __shfl_xor(v,  2, 64);
      v += __shfl_xor(v,  1, 64);
      acc[i][b] = v;
    }
  }
  if (s == 0){
    #pragma unroll
    for (int i=0;i<2;++i)
      #pragma unroll
      for (int b=0;b<8;++b)
        sm[OFF_EX + ((((pos<<1)+i)<<3) | b)] = acc[i][b];
  }
  __syncthreads();
  return (tid < 256) ? sm[OFF_EX + tid] : 0.f;
}

// GEMM tile: out[row 0..31][b 0..7] = sum_k Wlds[row][k] * X[b][k]
// XMODE 0: X = xsrc (sc1). XMODE 1: X = [attc*(1/S) | xpre(prefetched)].
template<int K, int XMODE>
__device__ float gemm32x8_lds(float* sm, const __half* __restrict__ wlds,
                              const float* __restrict__ xsrc,
                              const float* __restrict__ attc_cur,
                              const float* __restrict__ S_cur,
                              const float4* __restrict__ xpre)
{
  constexpr int NCH = K >> 8;
  const int tid = threadIdx.x;
  const int s = tid & 31, pos = tid >> 5;
  float acc[2][8];
  #pragma unroll
  for (int i=0;i<2;++i)
    #pragma unroll
    for (int b=0;b<8;++b) acc[i][b] = 0.f;

  const int xb = tid >> 6, xcol = (tid & 63) << 2;
  float4 xreg[NCH];
  if constexpr (XMODE == 0){
    #pragma unroll
    for (int ch=0; ch<NCH; ++ch)
      xreg[ch] = ldg4_sc1(xsrc + (size_t)xb*K + (ch<<8) + xcol);
  } else {
    float xsc = 1.f / ldg_sc1(S_cur + xb);
    #pragma unroll
    for (int ch=0; ch<2; ++ch){
      float4 v = ldg4_sc1(attc_cur + (xb<<9) + (ch<<8) + xcol);
      v.x*=xsc; v.y*=xsc; v.z*=xsc; v.w*=xsc;
      xreg[ch] = v;
    }
    #pragma unroll
    for (int ch=2; ch<NCH; ++ch) xreg[ch] = xpre[ch-2];
  }
  *(float4*)&sm[OFF_X0 + (xb<<8) + xcol] = xreg[0];
  __syncthreads();
  #pragma unroll
  for (int ch=0; ch<NCH; ++ch){
    if (ch+1 < NCH)
      *(float4*)&sm[(((ch+1)&1) ? OFF_X1 : OFF_X0) + (xb<<8) + xcol] = xreg[(ch+1 < NCH) ? ch+1 : 0];
    const float* xbase = &sm[((ch&1) ? OFF_X1 : OFF_X0)];
    const __half* wch = wlds + (ch<<8);
    #pragma unroll
    for (int j=0;j<2;++j){
      const int k = (j<<7) + (s<<2);
      float4 xv[8];
      #pragma unroll
      for (int b=0;b<8;++b) xv[b] = *(const float4*)&xbase[(b<<8) + k];
      #pragma unroll
      for (int i=0;i<2;++i){
        const int row = (pos<<1) + i;
        uint2 w2 = *(const uint2*)&wch[(size_t)row*K + k];
        __half2 ha = *reinterpret_cast<const __half2*>(&w2.x);
        __half2 hb = *reinterpret_cast<const __half2*>(&w2.y);
        float2 fa = __half22float2(ha);
        float2 fb = __half22float2(hb);
        #pragma unroll
        for (int b=0;b<8;++b){
          acc[i][b] = fmaf(fa.x, xv[b].x, acc[i][b]);
          acc[i][b] = fmaf(fa.y, xv[b].y, acc[i][b]);
          acc[i][b] = fmaf(fb.x, xv[b].z, acc[i][b]);
          acc[i][b] = fmaf(fb.y, xv[b].w, acc[i][b]);
        }
      }
    }
    __syncthreads();
  }
  return reduce_dot(sm, acc);
}

// issue the epilogue's LLC loads BEFORE the gemm so their latency hides
__device__ __forceinline__ float prefetch_gh(const float* gh, int u0){
  const int tid = threadIdx.x;
  if (tid >= 256) return 0.f;
  int row32 = tid >> 3, b = tid & 7;
  int gate = row32 >> 3, ul = row32 & 7;
  return ldg_sc1(&gh[(((gate<<10) + u0 + ul)<<3) + b]);
}
__device__ __forceinline__ float prefetch_h(const float* h, int u0){
  const int tid = threadIdx.x;
  if (tid >= 64) return 0.f;
  return ldg_sc1(&h[((tid&7)<<10) + u0 + (tid>>3)]);
}

__device__ void lstm_epilogue(float* sm, float dot, float ghb,
                              const float* __restrict__ bias, float hold,
                              float* __restrict__ h, float* __restrict__ c, int u0)
{
  const int tid = threadIdx.x;
  if (tid < 256){
    int row32 = tid >> 3;
    int gate = row32 >> 3, ul = row32 & 7;
    sm[OFF_EXG + tid] = dot + bias[(gate<<10) + u0 + ul] + ghb;
  }
  __syncthreads();
  if (tid < 64){
    float gi = sm[OFF_EXG + tid];
    float gf = sm[OFF_EXG + 64 + tid];
    float gg = sm[OFF_EXG + 128 + tid];
    float go = sm[OFF_EXG + 192 + tid];
    int ul2 = tid >> 3, b2 = tid & 7;
    int hi = (b2<<10) + u0 + ul2;
    float co = c[hi];               // block-private: cached
    float cn = fsig_(gf)*co + fsig_(gi)*ftanh_(gg);
    float hn = fsig_(go)*ftanh_(cn);
    c[hi] = 0.9f*cn + 0.1f*co;
    stg_sc1(&h[hi], 0.9f*hn + 0.1f*hold);
  }
}

// one output row per wave: rr = b*81 + r (r==80 -> stop)
__device__ void outstop_wave(int rr, int tp, int par,
    const float* __restrict__ feat_W, const float* __restrict__ stop_W,
    const float* __restrict__ stop_b, const float* __restrict__ h1,
    const float* __restrict__ attc, const float* __restrict__ iSw,
    float* __restrict__ d_out)
{
  if (rr >= 648) return;
  int b = rr / 81, r = rr - 81*b;
  int lane = threadIdx.x & 63;
  const float4* Wr = (const float4*)((r < 80) ? (feat_W + (size_t)r*1536) : stop_W);
  float inv = ldg_sc1(iSw + (par<<3) + b);
  float acc = 0.f, acc2 = 0.f;
  #pragma unroll
  for (int j=0;j<4;++j){
    int p = lane + (j<<6);
    float4 w = Wr[p], x = ldg4_sc1(h1 + (b<<10) + (p<<2));
    acc = fmaf(w.x,x.x, fmaf(w.y,x.y, fmaf(w.z,x.z, fmaf(w.w,x.w, acc))));
  }
  #pragma unroll
  for (int j=4;j<6;++j){
    int p = lane + (j<<6);
    float4 w = Wr[p], x = ldg4_sc1(attc + (par<<12) + (b<<9) + ((p-256)<<2));
    acc2 = fmaf(w.x,x.x, fmaf(w.y,x.y, fmaf(w.z,x.z, fmaf(w.w,x.w, acc2))));
  }
  acc += acc2 * inv;
  acc += __shfl_down(acc, 32, 64);
  acc += __shfl_down(acc, 16, 64);
  acc += __shfl_down(acc,  8, 64);
  acc += __shfl_down(acc,  4, 64);
  acc += __shfl_down(acc,  2, 64);
  acc += __shfl_down(acc,  1, 64);
  if (lane == 0){
    if (r < 80) d_out[((size_t)b*TDz + tp)*ODz + r] = acc;
    else        d_out[96000 + (size_t)b*TDz + tp] = acc + stop_b[0];
  }
}

extern "C" __global__ void __launch_bounds__(NT, 1) dec_kernel(
  const float* __restrict__ memory, const int* __restrict__ mlen, const float* __restrict__ targets,
  const float* __restrict__ W_mem, const float* __restrict__ W_q, const float* __restrict__ W_loc,
  const float* __restrict__ loc_f, const float* __restrict__ attn_v, const float* __restrict__ attn_b,
  const float* __restrict__ pre_W1, const float* __restrict__ pre_b1,
  const float* __restrict__ pre_W2, const float* __restrict__ pre_b2,
  const float* __restrict__ Wi0, const float* __restrict__ Wh0, const float* __restrict__ bl0,
  const float* __restrict__ Wi1, const float* __restrict__ Wh1, const float* __restrict__ bl1,
  const float* __restrict__ feat_W, const float* __restrict__ stop_W, const float* __restrict__ stop_b,
  float* __restrict__ d_out, float* __restrict__ ws)
{
  __shared__ float sm[SM_TOTF];
  const int blk = blockIdx.x, tid = threadIdx.x;

  float* Pw   = ws + OF_P;
  float* pmT  = ws + OF_PM;
  float* qw   = ws + OF_Q;
  float* uw   = ws + OF_U;
  float* cum  = ws + OF_CUM;
  float* attc = ws + OF_ATTC;
  float* Sw   = ws + OF_S;
  float* iSw  = ws + OF_INVS;
  float* h0 = ws + OF_H0; float* c0 = ws + OF_C0;
  float* h1 = ws + OF_H1; float* c1 = ws + OF_C1;
  float* gh0 = ws + OF_GH0; float* gh1 = ws + OF_GH1;
  int* bar = (int*)(ws + OF_BAR);
  int bt = 0;

  const bool is_attn = (blk < 128);
  const int ab  = blk >> 4;          // attention batch (blk<128)
  const int ai0 = (blk & 15) << 5;   // attention base position (32-wide)
  const int il  = tid & 31;          // position within slice
  const int ag  = tid >> 5;          // feature group (0..15)

  // ------------------------- INIT (every launch) ---------------------------
  {
    const int gs = NB*NT;
    const int gid = blk*NT + tid;
    for (int i = gid; i < 98304; i += gs) h0[i] = 0.f;    // h0,c0,h1,c1,gh0,gh1
    for (int i = gid; i < 1024;  i += gs) qw[i]  = 0.f;
    for (int i = gid; i < 4096;  i += gs) cum[i] = 0.f;
    for (int i = gid; i < 8192;  i += gs) attc[i] = 0.f;
    if (gid < 32) Sw[gid] = 0.f;                          // S + invS

    // persistent weights -> LDS fp16
    if (blk < 124){
      load_wtile<768, true >(&sm[OFF_WA], Wi0, blk<<3);
      load_wtile<1024,false>(&sm[OFF_WB], Wh0, blk<<5);
    } else if (blk < 128){
      load_wtile<768, true >(&sm[OFF_WA], Wi0, blk<<3);
      load_wtile<1024,false>(&sm[OFF_WB], W_q, (blk-124)<<5);
    } else {
      load_wtile<1024,false>(&sm[OFF_WG1], Wh1, (blk-128)<<5);
      load_wtile<1024,true >(&sm[OFF_WG2], Wi1, (blk-128)<<3);
    }

    if (is_attn){
      // pmT[a][il] = mem[ab, ai0+il, :] . W_mem[a,:] + attn_b[a]
      float pacc[8];
      #pragma unroll
      for (int j=0;j<8;++j) pacc[j] = 0.f;
      for (int dc=0; dc<4; ++dc){
        for (int idx = tid; idx < 4096; idx += NT){
          int r = idx >> 7, d = idx & 127;
          sm[r*129 + d] = memory[(size_t)((ab<<9)+ai0+r)*DINz + (dc<<7) + d];
        }
        __syncthreads();
        #pragma unroll
        for (int j=0;j<8;++j){
          int a = (ag<<3) + j;
          const float* wr = W_mem + (size_t)a*DINz + (dc<<7);
          const float* mr = &sm[il*129];
          float acc = 0.f;
          for (int d=0; d<128; d+=4){
            acc = fmaf(mr[d  ], wr[d  ], acc);
            acc = fmaf(mr[d+1], wr[d+1], acc);
            acc = fmaf(mr[d+2], wr[d+2], acc);
            acc = fmaf(mr[d+3], wr[d+3], acc);
          }
          pacc[j] += acc;
        }
        __syncthreads();
      }
      #pragma unroll
      for (int j=0;j<8;++j){
        int a = (ag<<3) + j;
        pmT[((size_t)blk<<12) + (a<<5) + il] = pacc[j] + attn_b[a];
      }
      // persistent slabs: F = W_loc @ filters, v
      for (int idx = tid; idx < ATz*KFz; idx += NT){
        int a = idx / KFz, k = idx - a*KFz;
        float s2 = 0.f;
        #pragma unroll
        for (int c2=0;c2<LOCz;++c2) s2 = fmaf(W_loc[(a<<5)+c2], loc_f[c2*KFz+k], s2);
        sm[OFF_F + idx] = s2;
      }
      if (tid < 128) sm[OFF_V + tid] = attn_v[tid];
      __syncthreads();
    }

    // prenet for all (t,b) pairs; scratch in sm[0..1023]
    const int th = tid >> 8, t2 = tid & 255, base = th << 9;
    for (int it=0; it<3; ++it){
      int pp = (blk<<1) + th + (it<<9);
      bool act = pp < 1200;
      if (act && t2 < ODz){
        int tt = pp >> 3, bb = pp & 7;
        sm[base + t2] = (tt==0) ? 0.f : targets[((size_t)bb*TDz + (tt-1))*ODz + t2];
      }
      __syncthreads();
      if (act){
        float a1 = pre_b1[t2];
        for (int k=0;k<ODz;++k) a1 = fmaf(pre_W1[t2*ODz+k], sm[base+k], a1);
        sm[base + 128 + t2] = fmaxf(a1, 0.f);
      }
      __syncthreads();
      if (act){
        float a2 = pre_b2[t2];
        for (int k=0;k<PREz;++k) a2 = fmaf(pre_W2[(t2<<8)+k], sm[base+128+k], a2);
        Pw[((size_t)pp<<8) + t2] = fmaxf(a2, 0.f);
      }
      __syncthreads();
    }
  }
  grid_barrier_heavy(bar, ++bt);

  // ------------------------------ MAIN LOOP (3 phases) ---------------------
  for (int t = 0; t < TDz; ++t){
    const int cur = t & 1, prv = cur ^ 1;

    // ---- P1: attention (0-127, 32 pos each, + P2 prefetch) | gh1 (128-255)
    float p2_ghb = 0.f, p2_hold = 0.f;
    float4 p2_x[5];
    if (is_attn){
      {  // prefetch P2 operands (all written at/before P3(t-1): stable now)
        const int u0 = blk << 3;
        const int xb = tid >> 6, xcol = (tid & 63) << 2;
        p2_ghb  = prefetch_gh(gh0, u0);
        p2_hold = prefetch_h(h0, u0);
        p2_x[0] = *(const float4*)(Pw + ((size_t)t<<11) + (xb<<8) + xcol);
        #pragma unroll
        for (int c=0;c<4;++c)
          p2_x[1+c] = ldg4_sc1(h0 + (xb<<10) + (c<<8) + xcol);
      }
      if (tid < 62){
        int gi = ai0 - 15 + tid;
        sm[OFF_CW + tid] = (gi >= 0 && gi < TE) ? ldg_sc1(&cum[(ab<<9)+gi]) : 0.f;
      }
      if (tid < 128) sm[OFF_QS + tid] = ldg_sc1(&qw[(tid<<3) + ab]);
      __syncthreads();
      float part = 0.f;
      #pragma unroll
      for (int j=0;j<8;++j){
        int a = (ag<<3) + j;
        const float* fb = &sm[OFF_F + a*KFz];
        float conv = 0.f;
        #pragma unroll
        for (int k=0;k<KFz;++k) conv = fmaf(fb[k], sm[OFF_CW + il + k], conv);
        float pv = pmT[((size_t)blk<<12) + (a<<5) + il];
        part = fmaf(sm[OFF_V + a], ftanh_(pv + sm[OFF_QS + a] + conv), part);
      }
      sm[OFF_PART + il*17 + ag] = part;
      __syncthreads();
      if (tid < 32){
        float e = 0.f;
        #pragma unroll
        for (int k=0;k<16;++k) e += sm[OFF_PART + tid*17 + k];
        int gi = ai0 + tid;
        float uu = (gi < mlen[ab]) ? __expf(e) : 0.f;
        stg_sc1(&uw[(ab<<9)+gi], uu);
        sm[OFF_UU + tid] = uu;
      }
      __syncthreads();
      if (tid == 0){
        float ssum = 0.f;
        #pragma unroll
        for (int k=0;k<32;++k) ssum += sm[OFF_UU + k];
        atomicAdd(&Sw[(cur<<3)+ab], ssum);
      }
      {
        float acc = 0.f;
        const float* mrow = memory + (size_t)((ab<<9)+ai0)*DINz + tid;
        #pragma unroll 8
        for (int i=0;i<32;++i)
          acc = fmaf(sm[OFF_UU + i], mrow[(size_t)i*DINz], acc);
        atomicAdd(&attc[(cur<<12) + (ab<<9) + tid], acc);
      }
    } else {
      const int tile = blk - 128;
      float dot = gemm32x8_lds<1024,0>(sm, (const __half*)&sm[OFF_WG1], h1,
                                       nullptr, nullptr, nullptr);
      if (tid < 256) stg_sc1(&gh1[(tile<<8) + tid], dot);
    }
    // P1-end: blocks 136-254 arrive-only (outstop/idle read nothing P1 wrote);
    // scanner 255 and waiters 0-135 do the full barrier.
    if (blk < 136 || blk == 255) grid_barrier(bar, ++bt);
    else                         grid_barrier_arrive(bar, ++bt);

    // ---- P2: LSTM0 (0-127) | attw/cum (128-135) | outstop t-1 (136-216) ---
    if (blk < 128){
      const int u0 = blk << 3;
      float dot = gemm32x8_lds<768,1>(sm, (const __half*)&sm[OFF_WA], nullptr,
                                      attc + (cur<<12), Sw + (cur<<3), p2_x);
      lstm_epilogue(sm, dot, p2_ghb, bl0, p2_hold, h0, c0, u0);
    } else if (blk < 136){
      const int b = blk - 128;
      float Sv = __hip_atomic_load(&Sw[(cur<<3)+b], __ATOMIC_RELAXED, AG);
      float inv = 1.f / Sv;
      if (tid == 0) stg_sc1(&iSw[(cur<<3)+b], inv);
      for (int i = tid; i < TE; i += NT){
        float u = ldg_sc1(&uw[(b<<9)+i]);
        float w = u * inv;
        d_out[97200 + ((size_t)b*TDz + t)*TE + i] = w;
        stg_sc1(&cum[(b<<9)+i], ldg_sc1(&cum[(b<<9)+i]) + w);
      }
    } else if (blk < 217){
      if (t > 0)
        outstop_wave((blk-136)*8 + (tid>>6), t-1, prv,
                     feat_W, stop_W, stop_b, h1, attc, iSw, d_out);
    }
    grid_barrier(bar, ++bt);

    // ---- P3: gh0 0-123 | Wq + zero duties (124-127) |
    //          LSTM1 + gh0 tail row (128-255) -----------------------------
    if (blk < 124){
      float dot = gemm32x8_lds<1024,0>(sm, (const __half*)&sm[OFF_WB], h0,
                                       nullptr, nullptr, nullptr);
      if (tid < 256) stg_sc1(&gh0[(blk<<8) + tid], dot);
    } else if (blk < 128){
      const int rt = blk - 124;
      float dot = gemm32x8_lds<1024,0>(sm, (const __half*)&sm[OFF_WB], h0,
                                       nullptr, nullptr, nullptr);
      if (tid < 256) stg_sc1(&qw[(rt<<8) + tid], dot);
      const int zbase = (prv<<12) + (rt<<10);
      for (int i = tid; i < 1024; i += NT) stg_sc1(&attc[zbase + i], 0.f);
      if (rt == 0 && tid < 8) stg_sc1(&Sw[(prv<<3)+tid], 0.f);
    } else {
      const int u0 = (blk - 128) << 3;
      const int blkL = blk - 128;
      // inline gh0 tail: row 3968+blkL = Wh0 row . h0[b] for b=0..7.
      {
        const int xb = tid >> 6, xcol = (tid & 63) << 2;
        const float* wr = Wh0 + (size_t)(3968 + blkL)*1024;
        float tp_ = 0.f;
        #pragma unroll
        for (int c=0;c<4;++c){
          float4 w = *(const float4*)(wr + (c<<8) + xcol);
          float4 x = ldg4_sc1(h0 + (xb<<10) + (c<<8) + xcol);
          tp_ = fmaf(w.x,x.x, fmaf(w.y,x.y, fmaf(w.z,x.z, fmaf(w.w,x.w, tp_))));
        }
        tp_ += __shfl_down(tp_, 32, 64);
        tp_ += __shfl_down(tp_, 16, 64);
        tp_ += __shfl_down(tp_,  8, 64);
        tp_ += __shfl_down(tp_,  4, 64);
        tp_ += __shfl_down(tp_,  2, 64);
        tp_ += __shfl_down(tp_,  1, 64);
        if ((tid & 63) == 0) stg_sc1(&gh0[((3968 + blkL)<<3) + xb], tp_);
      }
      float ghb  = prefetch_gh(gh1, u0);
      float hold = prefetch_h(h1, u0);
      float dot = gemm32x8_lds<1024,0>(sm, (const __half*)&sm[OFF_WG2], h0,
                                       nullptr, nullptr, nullptr);
      lstm_epilogue(sm, dot, ghb, bl1, hold, h1, c1, u0);
    }
    grid_barrier(bar, ++bt);
  }

  // final out/stop for t = 149 (parity 1)
  if (blk >= 136 && blk < 217)
    outstop_wave((blk-136)*8 + (tid>>6), TDz-1, 1,
                 feat_W, stop_W, stop_b, h1, attc, iSw, d_out);
}

extern "C" void kernel_launch(void* const* d_in, const int* in_sizes, int n_in,
                              void* d_out, int out_size, void* d_ws, size_t ws_size,
                              hipStream_t stream)
{
  (void)in_sizes; (void)n_in; (void)out_size; (void)ws_size;
  (void)hipMemsetAsync((char*)d_ws + (size_t)OF_BAR*4, 0, 18432, stream);
  dec_kernel<<<dim3(NB), dim3(NT), 0, stream>>>(
    (const float*)d_in[0],  (const int*)d_in[1],   (const float*)d_in[2],
    (const float*)d_in[3],  (const float*)d_in[4],  (const float*)d_in[5],
    (const float*)d_in[6],  (const float*)d_in[7],  (const float*)d_in[8],
    (const float*)d_in[9],  (const float*)d_in[10], (const float*)d_in[11], (const float*)d_in[12],
    (const float*)d_in[13], (const float*)d_in[14], (const float*)d_in[15],
    (const float*)d_in[16], (const float*)d_in[17], (const float*)d_in[18],
    (const float*)d_in[19], (const float*)d_in[20], (const float*)d_in[21],
    (float*)d_out, (float*)d_ws);
}